// Round 5
// baseline (84.683 us; speedup 1.0000x reference)
//
#include <hip/hip_runtime.h>

// PiecewiseChebyshevSeries — R5: prepass f16 table + even/odd recurrence, 3x probe.
// K_kernel = (dur - 58.5 - prepass)/3.
//
// 1) Prepass converts cheb f32 -> f16 into d_ws in the padded row-stride-40
//    LDS layout, so main-kernel staging is a raw 20KB b128 copy (no cvt, less L2).
// 2) T_{m+2} = 2*T2*T_m - T_{m-2}: even/odd split -> 4 independent ~15-deep
//    FMA chains (was 2x ~31-deep), same op count, half the dependent latency.

constexpr int B = 16;
constexpr int X = 256;
constexpr int Y = 32;
constexpr int N = 131072;

constexpr int THREADS = 256;
constexpr int EPT = 4;                    // elements per thread
constexpr int EPB = THREADS * EPT;        // 1024
constexpr int BLOCKS_PER_B = N / EPB;     // 128
constexpr int LSTR = 40;                  // f16 row stride (80 B; rows hit all 8 bank-quads)

typedef _Float16 half4v __attribute__((ext_vector_type(4)));
typedef _Float16 half8v __attribute__((ext_vector_type(8)));

// ---- prepass: cheb f32 -> f16 padded table in ws ----
__global__ __launch_bounds__(256)
void cvt_table(const float* __restrict__ cheb, _Float16* __restrict__ table)
{
    int i = blockIdx.x * 256 + threadIdx.x;        // float4 index, 0..32767
    float4 v = reinterpret_cast<const float4*>(cheb)[i];
    int bi  = i >> 11;                              // 2048 float4 per b
    int f4i = i & 2047;
    int row = f4i >> 3;
    int q   = f4i & 7;
    half4v hv = { (_Float16)v.x, (_Float16)v.y, (_Float16)v.z, (_Float16)v.w };
    *reinterpret_cast<half4v*>(&table[((size_t)bi * X + row) * LSTR + q * 4]) = hv;
}

__device__ __forceinline__ float eval1(const _Float16* __restrict__ lds, float zj)
{
    // Decode: u = z + 1; x = floor(u/2); t = (u - 2x) - 1   (matches ref divmod)
    float u  = zj + 1.0f;
    float xf = floorf(u * 0.5f);
    int   xi = (int)xf;
    float t  = fmaf(-2.0f, xf, u) - 1.0f;

    const half8v* c8 = reinterpret_cast<const half8v*>(lds + xi * LSTR);
    half8v h[4];
    #pragma unroll
    for (int i = 0; i < 4; ++i) h[i] = c8[i];      // 4x ds_read_b128

#define CF(m) ((float)h[(m) >> 3][(m) & 7])
    float t2 = t + t;
    float s  = fmaf(t2, t, -1.0f);                 // T2
    float s2 = s + s;
    float Ep = 1.0f, Ec = s;                       // T0, T2
    float Op = t,    Oc = fmaf(s2, t, -t);         // T1, T3
    float accE = fmaf(CF(2), s,  CF(0));
    float accO = fmaf(CF(3), Oc, CF(1) * t);
    #pragma unroll
    for (int k = 2; k <= 15; ++k) {                // T_{2k}, T_{2k+1}
        float En = fmaf(s2, Ec, -Ep); accE = fmaf(CF(2 * k),     En, accE); Ep = Ec; Ec = En;
        float On = fmaf(s2, Oc, -Op); accO = fmaf(CF(2 * k + 1), On, accO); Op = Oc; Oc = On;
    }
#undef CF
    return accE + accO;
}

__global__ __launch_bounds__(THREADS, 8)
void cheb_eval(const float* __restrict__ z,
               const _Float16* __restrict__ table,
               float* __restrict__ out)
{
    __shared__ __align__(16) _Float16 lds[X * LSTR];   // 20480 B -> 8 blocks/CU
    const int bid   = blockIdx.x;
    const int b     = bid >> 7;
    const int chunk = bid & 127;
    const int tid   = threadIdx.x;

    // Raw 20480B copy: 1280 x 16B chunks, 5 iterations. Linear b128 writes
    // (lane l -> quad l%8) are bank-uniform -> conflict-free.
    const ulonglong2* src = reinterpret_cast<const ulonglong2*>(table + (size_t)b * X * LSTR);
    ulonglong2*       dst = reinterpret_cast<ulonglong2*>(lds);
    #pragma unroll
    for (int k = 0; k < 5; ++k) {
        int idx = k * THREADS + tid;
        dst[idx] = src[idx];
    }
    __syncthreads();

    const float4* zb4 = reinterpret_cast<const float4*>(z   + (size_t)b * N + (size_t)chunk * EPB);
    float4*       ob4 = reinterpret_cast<float4*>      (out + (size_t)b * N + (size_t)chunk * EPB);

    float4 zv = zb4[tid];
    float r0 = eval1(lds, zv.x);
    float r1 = eval1(lds, zv.y);
    float r2 = eval1(lds, zv.z);
    float r3 = eval1(lds, zv.w);
    ob4[tid] = make_float4(r0, r1, r2, r3);
}

extern "C" void kernel_launch(void* const* d_in, const int* in_sizes, int n_in,
                              void* d_out, int out_size, void* d_ws, size_t ws_size,
                              hipStream_t stream) {
    const float* z    = (const float*)d_in[0];
    const float* cheb = (const float*)d_in[1];
    float*       out  = (float*)d_out;
    _Float16*    tab  = (_Float16*)d_ws;           // 327,680 B used

    hipLaunchKernelGGL(cvt_table, dim3(128), dim3(256), 0, stream, cheb, tab);
    dim3 grid(B * BLOCKS_PER_B);                   // 2048 blocks
    dim3 block(THREADS);
    // 3 identical launches (probe): K = (dur - overhead - prepass)/3.
    hipLaunchKernelGGL(cheb_eval, grid, block, 0, stream, z, tab, out);
    hipLaunchKernelGGL(cheb_eval, grid, block, 0, stream, z, tab, out);
    hipLaunchKernelGGL(cheb_eval, grid, block, 0, stream, z, tab, out);
}

// Round 6
// 65.574 us; speedup vs baseline: 1.2914x; 1.2914x over previous
//
#include <hip/hip_runtime.h>

// PiecewiseChebyshevSeries — R6: final single-launch config.
// out[b,n] = sum_m cheb[b, x_idx, m] * T_m(t);  cos(m*arccos t) == T_m(t).
// - f16 coeff table staged to LDS (20480 B, stride-40 rows -> 8 bank-groups,
//   bijective mod 8) -> 4 blocks x 16 waves... = 32 waves/CU, 100% occupancy.
// - block 512 / grid 1024: halves staging L2 traffic vs 256/2048.
// - even/odd recurrence T_{m+2} = 2*T2*T_m - T_{m-2}: 4 independent ~15-deep
//   FMA chains; (float)h casts fold into v_fma_mix.
// K_kernel ~ 7 us; dur_us floor dominated by ~58.5 us harness re-poison fills.

constexpr int B = 16;
constexpr int X = 256;
constexpr int Y = 32;
constexpr int N = 131072;

constexpr int THREADS = 512;
constexpr int EPT = 4;                    // elements per thread
constexpr int EPB = THREADS * EPT;        // 2048
constexpr int BLOCKS_PER_B = N / EPB;     // 64
constexpr int LSTR = 40;                  // f16 row stride (80 B)

typedef _Float16 half4v __attribute__((ext_vector_type(4)));
typedef _Float16 half8v __attribute__((ext_vector_type(8)));

__device__ __forceinline__ float eval1(const _Float16* __restrict__ lds, float zj)
{
    // Decode: u = z + 1; x = floor(u/2); t = (u - 2x) - 1   (matches ref divmod)
    float u  = zj + 1.0f;
    float xf = floorf(u * 0.5f);
    int   xi = (int)xf;
    float t  = fmaf(-2.0f, xf, u) - 1.0f;

    const half8v* c8 = reinterpret_cast<const half8v*>(lds + xi * LSTR);
    half8v h[4];
    #pragma unroll
    for (int i = 0; i < 4; ++i) h[i] = c8[i];      // 4x ds_read_b128

#define CF(m) ((float)h[(m) >> 3][(m) & 7])
    float t2 = t + t;
    float s  = fmaf(t2, t, -1.0f);                 // T2
    float s2 = s + s;
    float Ep = 1.0f, Ec = s;                       // T0, T2
    float Op = t,    Oc = fmaf(s2, t, -t);         // T1, T3
    float accE = fmaf(CF(2), s,  CF(0));
    float accO = fmaf(CF(3), Oc, CF(1) * t);
    #pragma unroll
    for (int k = 2; k <= 15; ++k) {                // T_{2k}, T_{2k+1}
        float En = fmaf(s2, Ec, -Ep); accE = fmaf(CF(2 * k),     En, accE); Ep = Ec; Ec = En;
        float On = fmaf(s2, Oc, -Op); accO = fmaf(CF(2 * k + 1), On, accO); Op = Oc; Oc = On;
    }
#undef CF
    return accE + accO;
}

__global__ __launch_bounds__(THREADS, 8)
void cheb_eval(const float* __restrict__ z,
               const float* __restrict__ cheb,
               float* __restrict__ out)
{
    __shared__ __align__(16) _Float16 lds[X * LSTR];   // 20480 B
    const int bid   = blockIdx.x;
    const int b     = bid >> 6;            // / BLOCKS_PER_B
    const int chunk = bid & 63;
    const int tid   = threadIdx.x;

    // Stage cheb[b] (256 x 32 f32 = 32 KiB) -> LDS f16, row stride 40.
    const float4* src = reinterpret_cast<const float4*>(cheb + (size_t)b * (X * Y));
    #pragma unroll
    for (int k = 0; k < (X * Y / 4) / THREADS; ++k) {   // 4 iterations
        int f4  = k * THREADS + tid;                    // 0..2047
        float4 v = src[f4];
        int row = f4 >> 3;
        int q   = f4 & 7;
        half4v hv = { (_Float16)v.x, (_Float16)v.y, (_Float16)v.z, (_Float16)v.w };
        *reinterpret_cast<half4v*>(&lds[row * LSTR + q * 4]) = hv;   // 8B ds_write
    }
    __syncthreads();

    const float4* zb4 = reinterpret_cast<const float4*>(z   + (size_t)b * N + (size_t)chunk * EPB);
    float4*       ob4 = reinterpret_cast<float4*>      (out + (size_t)b * N + (size_t)chunk * EPB);

    float4 zv = zb4[tid];
    float r0 = eval1(lds, zv.x);
    float r1 = eval1(lds, zv.y);
    float r2 = eval1(lds, zv.z);
    float r3 = eval1(lds, zv.w);
    ob4[tid] = make_float4(r0, r1, r2, r3);
}

extern "C" void kernel_launch(void* const* d_in, const int* in_sizes, int n_in,
                              void* d_out, int out_size, void* d_ws, size_t ws_size,
                              hipStream_t stream) {
    const float* z    = (const float*)d_in[0];
    const float* cheb = (const float*)d_in[1];
    float*       out  = (float*)d_out;
    dim3 grid(B * BLOCKS_PER_B);   // 1024 blocks, 4/CU -> 32 waves/CU
    dim3 block(THREADS);
    hipLaunchKernelGGL(cheb_eval, grid, block, 0, stream, z, cheb, out);
}